// Round 5
// baseline (2024.811 us; speedup 1.0000x reference)
//
#include <hip/hip_runtime.h>
#include <cstdint>
#include <cstddef>

// ---------------------------------------------------------------------------
// LinearSGD fused pipeline for MI355X (gfx950).  ALL I/O is float32.
// Precision: split-bf16 (hi+lo) at every MFMA (truncation split:
//   hi = trunc_bf16(x), lo = trunc_bf16(x - hi), |err| <= 2^-16 |x|),
//   A@B ~= Ah@Bh + Ah@Bl + Al@Bh  (3-term, f32 accum).
// Round 5:
//   - gemm3v BMODE1: T3/T4 "minimum 2-phase" double-buffer — stage next
//     K-tile via global_load_lds BEFORE compute, counted s_waitcnt vmcnt(8)
//     + raw s_barrier (loads stay in flight across barriers; no full drain).
//     64 KB LDS (2 bufs), BMODE0 (v-gemm) keeps the old 1-phase path.
//   - scan v4: kh_s/kl_s LDS tiles ELIMINATED — e-A and qk-B k-fragments
//     are per-wave rows, loaded straight from global (L3-warm) and
//     prefetched one chunk ahead (like q).  Barriers restructured:
//     bar0 -> {kT/v/dec LDS writes  ||  e/qk/zq MFMA from regs} -> bar1 ->
//     e-fin/S -> bar2 -> Se/dw/W-update.  LDS 96 KB.  Math bit-identical.
// ---------------------------------------------------------------------------

typedef unsigned short u16b;
typedef uint32_t u32;
typedef __attribute__((ext_vector_type(8))) __bf16 bf16x8;
typedef __attribute__((ext_vector_type(4))) float  f32x4;

__device__ __forceinline__ float bf2f(u16b v){
  union { float f; uint32_t u; } x; x.u = ((uint32_t)v) << 16; return x.f;
}
// truncation-based split: cheap (no rounding chains), hi+lo ~ f to 2^-16
__device__ __forceinline__ void split2(float f, u16b& h, u16b& l){
  uint32_t u = __float_as_uint(f);
  float hf = __uint_as_float(u & 0xFFFF0000u);
  h = (u16b)(u >> 16);
  l = (u16b)(__float_as_uint(f - hf) >> 16);
}
__device__ __forceinline__ f32x4 mfma16(bf16x8 a, bf16x8 b, f32x4 c){
  return __builtin_amdgcn_mfma_f32_16x16x32_bf16(a, b, c, 0, 0, 0);
}
// async global->LDS, 16B per lane (dest = wave-uniform base + lane*16)
__device__ __forceinline__ void gl16(const void* g, void* l){
  __builtin_amdgcn_global_load_lds(
      (const __attribute__((address_space(1))) u32*)g,
      (__attribute__((address_space(3))) u32*)l, 16, 0, 0);
}
// unpack 8 packed u32 (h<<16|l) -> hi bf16x8 + lo bf16x8 via v_perm
__device__ __forceinline__ void unpack8(const u32* p, bf16x8& hv, bf16x8& lv){
  uint4 P0 = *(const uint4*)p;
  uint4 P1 = *(const uint4*)(p + 4);
  union { u32 w[4]; bf16x8 v; } H, L;
  H.w[0] = __builtin_amdgcn_perm(P0.y, P0.x, 0x07060302u);
  H.w[1] = __builtin_amdgcn_perm(P0.w, P0.z, 0x07060302u);
  H.w[2] = __builtin_amdgcn_perm(P1.y, P1.x, 0x07060302u);
  H.w[3] = __builtin_amdgcn_perm(P1.w, P1.z, 0x07060302u);
  L.w[0] = __builtin_amdgcn_perm(P0.y, P0.x, 0x05040100u);
  L.w[1] = __builtin_amdgcn_perm(P0.w, P0.z, 0x05040100u);
  L.w[2] = __builtin_amdgcn_perm(P1.y, P1.x, 0x05040100u);
  L.w[3] = __builtin_amdgcn_perm(P1.w, P1.z, 0x05040100u);
  hv = H.v; lv = L.v;
}

// ---------------------------------------------------------------------------
// f32 -> (hi,lo) bf16 split, 8 elems/thread, fully coalesced.
// ---------------------------------------------------------------------------
__global__ __launch_bounds__(256) void split_kernel(
    const float* __restrict__ src, u16b* __restrict__ dh, u16b* __restrict__ dl,
    int n8)
{
  int i = blockIdx.x*256 + threadIdx.x;
  if (i >= n8) return;
  const float4* s4 = (const float4*)src;
  float4 a = s4[2*(size_t)i], b = s4[2*(size_t)i + 1];
  float f[8] = {a.x,a.y,a.z,a.w,b.x,b.y,b.z,b.w};
  u16b h[8], l[8];
#pragma unroll
  for (int j = 0; j < 8; j++) split2(f[j], h[j], l[j]);
  *(uint4*)(dh + (size_t)i*8) = *(const uint4*)h;
  *(uint4*)(dl + (size_t)i*8) = *(const uint4*)l;
}

// ---------------------------------------------------------------------------
// Split GEMM v3: C[M,N] = (Ah+Al)[M,Kd] @ (Bh+Bl)[N,Kd]^T, 3-term MFMA.
// BMODE 1: 2-phase dbuf (counted vmcnt(8) + raw barriers, loads in flight
// across barriers).  BMODE 0: B f32 split in-kernel, old 1-phase loop.
// 128x128 tile, 4 waves 2x2, BK=32.  T2 XOR-swizzled [.][32] tiles
// (pre-swizzled global source col; reads XOR the slot).  Coalesced
// LDS-bounce epilogue.  OUTMODE 0: (Ch,Cl) split; 1: Cf f32.
// ---------------------------------------------------------------------------
template<int BMODE, int OUTMODE>
__global__ __launch_bounds__(256) void gemm3v(
    const u16b* __restrict__ Ah, const u16b* __restrict__ Al,
    const u16b* __restrict__ Bh, const u16b* __restrict__ Bl,
    const float* __restrict__ Bf,
    u16b* __restrict__ Ch, u16b* __restrict__ Cl, float* __restrict__ Cf,
    int M, int N, int Kd, float alpha)
{
  (void)M;
  __shared__ __align__(16) u16b smem[32768];   // 64 KB: 2 staging bufs / bounce

  // XCD-aware bijective swizzle (gridDim.x % 8 == 0)
  const int cpx = gridDim.x >> 3;
  const int flat = blockIdx.x;
  const int swz = (flat & 7) * cpx + (flat >> 3);
  const int nb = N >> 7;
  const int m0 = (swz / nb) * 128;
  const int n0 = (swz % nb) * 128;

  const int tid  = threadIdx.x;
  const int wid  = tid >> 6;
  const int lane = tid & 63;
  const int wm = (wid & 1) * 64;
  const int wn = (wid >> 1) * 64;
  const int rw = lane & 15;
  const int kq = (lane >> 4) * 8;
  const int sx = ((rw >> 1) & 3) << 3;   // fragment-read swizzle XOR

  const int srow = tid >> 2;
  const int scol = ((tid & 3) * 8) ^ (((tid >> 3) & 3) << 3);
  const u16b* gA0 = Ah + (size_t)(m0 + srow)*Kd + scol;
  const u16b* gA1 = gA0 + (size_t)64*Kd;
  const u16b* gAl0 = Al + (size_t)(m0 + srow)*Kd + scol;
  const u16b* gAl1 = gAl0 + (size_t)64*Kd;

  f32x4 acc[4][4] = {};

  if constexpr (BMODE == 1){
    const u16b* gB0  = Bh + (size_t)(n0 + srow)*Kd + scol;
    const u16b* gB1  = gB0 + (size_t)64*Kd;
    const u16b* gBl0 = Bl + (size_t)(n0 + srow)*Kd + scol;
    const u16b* gBl1 = gBl0 + (size_t)64*Kd;

    auto stage = [&](int buf, int k0){
      u16b* base = smem + buf*16384;
      gl16(gA0  + k0, base + tid*8);
      gl16(gA1  + k0, base + 2048  + tid*8);
      gl16(gAl0 + k0, base + 4096  + tid*8);
      gl16(gAl1 + k0, base + 6144  + tid*8);
      gl16(gB0  + k0, base + 8192  + tid*8);
      gl16(gB1  + k0, base + 10240 + tid*8);
      gl16(gBl0 + k0, base + 12288 + tid*8);
      gl16(gBl1 + k0, base + 14336 + tid*8);
    };

    stage(0, 0);
    int cur = 0;
    for (int k0 = 0; k0 < Kd; k0 += 32, cur ^= 1){
      const u16b* Ahs = smem + cur*16384;
      const u16b* Als = Ahs + 4096;
      const u16b* Bhs = Ahs + 8192;
      const u16b* Bls = Ahs + 12288;
      if (k0 + 32 < Kd){
        stage(cur ^ 1, k0 + 32);              // next tile in flight
        asm volatile("s_waitcnt vmcnt(8)" ::: "memory");  // cur landed
      } else {
        asm volatile("s_waitcnt vmcnt(0)" ::: "memory");
      }
      __builtin_amdgcn_s_barrier();           // all waves: cur visible

      bf16x8 afh[4], afl[4], bfh[4], bfl[4];
#pragma unroll
      for (int i = 0; i < 4; i++){
        afh[i] = *(const bf16x8*)&Ahs[(wm + i*16 + rw)*32 + (kq ^ sx)];
        afl[i] = *(const bf16x8*)&Als[(wm + i*16 + rw)*32 + (kq ^ sx)];
      }
#pragma unroll
      for (int j = 0; j < 4; j++){
        bfh[j] = *(const bf16x8*)&Bhs[(wn + j*16 + rw)*32 + (kq ^ sx)];
        bfl[j] = *(const bf16x8*)&Bls[(wn + j*16 + rw)*32 + (kq ^ sx)];
      }
#pragma unroll
      for (int i = 0; i < 4; i++)
#pragma unroll
        for (int j = 0; j < 4; j++){
          f32x4 t = mfma16(afl[i], bfh[j], acc[i][j]);
          t = mfma16(afh[i], bfl[j], t);
          acc[i][j] = mfma16(afh[i], bfh[j], t);
        }
      __builtin_amdgcn_s_barrier();           // cur reads done -> reusable
    }
  } else {
    // ---- old 1-phase loop, B split in-kernel (v-projection only) ----
    u16b* Ahs = smem;
    u16b* Als = smem + 4096;
    u16b* Bhs = smem + 8192;
    u16b* Bls = smem + 12288;
    for (int k0 = 0; k0 < Kd; k0 += 32){
      float4 fb[4];
#pragma unroll
      for (int it = 0; it < 4; it++){
        int idx = it*256 + tid;
        int rr = idx >> 3, c4 = (idx & 7) * 4;
        fb[it] = *(const float4*)(Bf + (size_t)(n0 + rr) * Kd + k0 + c4);
      }
      __syncthreads();                     // prev-iter LDS reads done
      gl16(gA0  + k0, Ahs + tid*8);
      gl16(gA1  + k0, Ahs + 2048 + tid*8);
      gl16(gAl0 + k0, Als + tid*8);
      gl16(gAl1 + k0, Als + 2048 + tid*8);
#pragma unroll
      for (int it = 0; it < 4; it++){
        int idx = it*256 + tid;
        int rr = idx >> 3, c4 = (idx & 7) * 4;
        int cs = c4 ^ (((rr >> 1) & 3) << 3);   // swizzled store col
        float f[4] = {fb[it].x, fb[it].y, fb[it].z, fb[it].w};
        u16b h[4], l[4];
#pragma unroll
        for (int j = 0; j < 4; j++) split2(f[j], h[j], l[j]);
        *(uint2*)&Bhs[rr*32 + cs] = *(const uint2*)h;
        *(uint2*)&Bls[rr*32 + cs] = *(const uint2*)l;
      }
      __syncthreads();                     // tile ready

      bf16x8 afh[4], afl[4], bfh[4], bfl[4];
#pragma unroll
      for (int i = 0; i < 4; i++){
        afh[i] = *(const bf16x8*)&Ahs[(wm + i*16 + rw)*32 + (kq ^ sx)];
        afl[i] = *(const bf16x8*)&Als[(wm + i*16 + rw)*32 + (kq ^ sx)];
      }
#pragma unroll
      for (int j = 0; j < 4; j++){
        bfh[j] = *(const bf16x8*)&Bhs[(wn + j*16 + rw)*32 + (kq ^ sx)];
        bfl[j] = *(const bf16x8*)&Bls[(wn + j*16 + rw)*32 + (kq ^ sx)];
      }
#pragma unroll
      for (int i = 0; i < 4; i++)
#pragma unroll
        for (int j = 0; j < 4; j++){
          f32x4 t = mfma16(afl[i], bfh[j], acc[i][j]);
          t = mfma16(afh[i], bfl[j], t);
          acc[i][j] = mfma16(afh[i], bfh[j], t);
        }
    }
  }

  // ---- epilogue: LDS bounce for coalesced stores ----
  float* Bnc = (float*)smem;             // 32*132*4 = 16896 B (fits buf0)
  const int ccol  = lane & 15;
  const int cquad = lane >> 4;
  const int brb = ((wid & 1) << 4) + cquad*4;
  const int br2 = tid >> 3, c0 = (tid & 7) * 16;
#pragma unroll
  for (int i = 0; i < 4; i++){
    __syncthreads();
#pragma unroll
    for (int j = 0; j < 4; j++)
#pragma unroll
      for (int r = 0; r < 4; r++)
        Bnc[(brb + r)*132 + wn + j*16 + ccol] = acc[i][j][r];
    __syncthreads();
    const int rowg = m0 + ((br2 >> 4) << 6) + i*16 + (br2 & 15);
    float4 x0 = *(const float4*)&Bnc[br2*132 + c0];
    float4 x1 = *(const float4*)&Bnc[br2*132 + c0 + 4];
    float4 x2 = *(const float4*)&Bnc[br2*132 + c0 + 8];
    float4 x3 = *(const float4*)&Bnc[br2*132 + c0 + 12];
    float v[16] = {x0.x,x0.y,x0.z,x0.w, x1.x,x1.y,x1.z,x1.w,
                   x2.x,x2.y,x2.z,x2.w, x3.x,x3.y,x3.z,x3.w};
#pragma unroll
    for (int e = 0; e < 16; e++) v[e] *= alpha;
    if constexpr (OUTMODE == 0){
      u16b h[16], l[16];
#pragma unroll
      for (int e = 0; e < 16; e++) split2(v[e], h[e], l[e]);
      size_t off = (size_t)rowg * N + n0 + c0;
      *(uint4*)(Ch + off)     = *(const uint4*)&h[0];
      *(uint4*)(Ch + off + 8) = *(const uint4*)&h[8];
      *(uint4*)(Cl + off)     = *(const uint4*)&l[0];
      *(uint4*)(Cl + off + 8) = *(const uint4*)&l[8];
    } else {
      size_t off = (size_t)rowg * N + n0 + c0;
      *(float4*)(Cf + off)      = *(const float4*)&v[0];
      *(float4*)(Cf + off + 4)  = *(const float4*)&v[4];
      *(float4*)(Cf + off + 8)  = *(const float4*)&v[8];
      *(float4*)(Cf + off + 12) = *(const float4*)&v[12];
    }
  }
}

// ---------------------------------------------------------------------------
// eta/theta skinny projection (pure f32): per (b,t) row, 32 dots of 2048.
// ---------------------------------------------------------------------------
__global__ __launch_bounds__(256) void etatheta_kernel(
    const float* __restrict__ x, const float* __restrict__ Weta,
    const float* __restrict__ Wtheta, float* __restrict__ eta, float* __restrict__ theta)
{
  __shared__ float xr[2048];
  const int bt = blockIdx.x;
  const int b = bt >> 12, t = bt & 4095;
  const float* xp = x + (size_t)bt * 2048;
  for (int i = threadIdx.x; i < 2048; i += 256) xr[i] = xp[i];
  __syncthreads();
  const int wid = threadIdx.x >> 6, lane = threadIdx.x & 63;
  for (int oi = 0; oi < 8; oi++){
    int og = wid*8 + oi;
    const float* wrow = (og < 16) ? (Weta + (size_t)og*2048)
                                  : (Wtheta + (size_t)(og-16)*2048);
    float acc = 0.f;
    for (int d = lane; d < 2048; d += 64) acc += xr[d] * wrow[d];
#pragma unroll
    for (int off = 32; off; off >>= 1) acc += __shfl_down(acc, off);
    if (lane == 0){
      float s = 1.f / (1.f + expf(-acc));
      if (og < 16) eta  [((size_t)(b*16 + og     ))*4096 + t] = s;
      else         theta[((size_t)(b*16 + og - 16))*4096 + t] = 0.1f * s;
    }
  }
}

// ---------------------------------------------------------------------------
// Decay precompute: per (bh, chunk) of 64 t: lec = cumsum(log eta),
// elt = exp(lec), wt = exp(lec63 - lec) * theta.
// ---------------------------------------------------------------------------
__global__ __launch_bounds__(64) void decay_kernel(
    const float* __restrict__ eta, const float* __restrict__ th,
    float* __restrict__ lecb, float* __restrict__ eltb, float* __restrict__ wtb)
{
  const int bh = blockIdx.x, n = blockIdx.y, lane = threadIdx.x;
  size_t idx = (size_t)bh*4096 + n*64 + lane;
  float cum = logf(fmaxf(eta[idx], 1e-8f));
#pragma unroll
  for (int off = 1; off < 64; off <<= 1){
    float o = __shfl_up(cum, off);
    if (lane >= off) cum += o;
  }
  float lec63 = __shfl(cum, 63);
  lecb[idx] = cum;
  eltb[idx] = expf(cum);
  wtb[idx]  = expf(lec63 - cum) * th[idx];
}

// ---------------------------------------------------------------------------
// Chunk scan v4: no k LDS tile — e-A / qk-B fragments direct from global
// (per-wave rows, prefetched one chunk ahead).  kT packed u32 scatter,
// packed e/ew, swizzled S.  Barriers: bar0 -> {LDS stage || e/qk/zq MFMA}
// -> bar1 -> e-fin/S -> bar2 -> Se/dw/W-update.  LDS 96 KB, 1 block/CU.
// ---------------------------------------------------------------------------
#define WSTR 136
__global__ __launch_bounds__(512) void scan_kernel(
    const u16b* __restrict__ qh, const u16b* __restrict__ ql,
    const u16b* __restrict__ kh, const u16b* __restrict__ kl,
    const float* __restrict__ lecb, const float* __restrict__ eltb,
    const float* __restrict__ wtb,  const float* __restrict__ thb,
    float* vo)                                     // v in, outs out (aliased)
{
  __shared__ u32  kTp[128*68];                 // packed kT (h<<16|l)
  __shared__ u16b Wh[32*WSTR], Wl[32*WSTR];
  __shared__ u32  epk [32*68];                 // packed e^T [vv][t]
  __shared__ u32  ewpk[32*68];                 // packed (wt*e)^T
  __shared__ u16b Sh_s[64*72], Sl_s[64*72];    // XOR-swizzled cols
  __shared__ float v_s[64*36];
  __shared__ float dec_s[4*64];    // [0]=lec [1]=elt [2]=wt [3]=th

  const int bh = blockIdx.x;
  const int b = bh >> 4, h = bh & 15;
  const int v0 = blockIdx.y * 32;
  const int tid  = threadIdx.x;
  const int wid  = tid >> 6;       // 0..7
  const int tw   = wid & 3;        // t 16-row block
  const int jh   = wid >> 2;       // j/v 16-col half
  const int lane = tid & 63;
  const int rw = lane & 15;
  const int kq = (lane >> 4) * 8;
  const int ccol  = lane & 15;
  const int cquad = lane >> 4;

  for (int i = tid; i < 32*WSTR; i += 512){ Wh[i] = 0; Wl[i] = 0; }

  const size_t rowbase = (size_t)b * 4096;
  const size_t decbase = (size_t)bh * 4096;
  const int sr0 = tid >> 4;             // kT staging row (it=0), +32 for it=1
  const int sc8 = (tid & 15) * 8;       // kT staging col
  const int vr  = tid >> 3;             // v staging row
  const int vc4 = (tid & 7) * 4;        // v staging col
  const float* dsrc = (tid < 64) ? lecb : (tid < 128) ? eltb
                     : (tid < 192) ? wtb : thb;
  const size_t doff = decbase + (tid & 63);

  // per-wave global fragment row bases (elements)
  const size_t fragA  = (rowbase + tw*16 + rw) * 2048 + (size_t)h*128;
  const size_t fragB0 = (rowbase + (jh*2+0)*16 + rw) * 2048 + (size_t)h*128;
  const size_t fragB1 = (rowbase + (jh*2+1)*16 + rw) * 2048 + (size_t)h*128;

  // ---- prefetch registers ----
  uint4 kuh[2], kul[2];
  float4 vreg;
  float dreg = 0.f;
  bf16x8 qch[4], qcl[4];
  bf16x8 kah[4], kal[4];
  bf16x8 kbh[2][4], kbl[2][4];

  // ---- prologue: load chunk 0 ----
  {
#pragma unroll
    for (int it = 0; it < 2; it++){
      int r = it*32 + sr0;
      size_t g = (rowbase + r) * 2048 + (size_t)h*128 + sc8;
      kuh[it] = *(const uint4*)&kh[g];
      kul[it] = *(const uint4*)&kl[g];
    }
    { size_t g = (rowbase + vr) * 2048 + (size_t)h*128 + v0 + vc4;
      vreg = *(const float4*)&vo[g]; }
    if (tid < 256) dreg = dsrc[doff];
#pragma unroll
    for (int ks = 0; ks < 4; ks++){
      qch[ks] = *(const bf16x8*)(qh + fragA + ks*32 + kq);
      qcl[ks] = *(const bf16x8*)(ql + fragA + ks*32 + kq);
      kah[ks] = *(const bf16x8*)(kh + fragA + ks*32 + kq);
      kal[ks] = *(const bf16x8*)(kl + fragA + ks*32 + kq);
      kbh[0][ks] = *(const bf16x8*)(kh + fragB0 + ks*32 + kq);
      kbl[0][ks] = *(const bf16x8*)(kl + fragB0 + ks*32 + kq);
      kbh[1][ks] = *(const bf16x8*)(kh + fragB1 + ks*32 + kq);
      kbl[1][ks] = *(const bf16x8*)(kl + fragB1 + ks*32 + kq);
    }
  }

  for (int n = 0; n < 64; n++){
    const int tbase = n * 64;
    const size_t nx = (size_t)(tbase + 64) * 2048;   // next-chunk elem offset
    __syncthreads();                    // bar0: prev Se/dw/W-update done

    // ---- LDS stage from regs: packed kT scatter + v + dec ----
#pragma unroll
    for (int it = 0; it < 2; it++){
      int r = it*32 + sr0;
      const u32* hw = (const u32*)&kuh[it];
      const u32* lw = (const u32*)&kul[it];
      const int kx = ((sc8 >> 3) & 3) << 3;
#pragma unroll
      for (int w = 0; w < 4; w++){
        u32 pe = __builtin_amdgcn_perm(hw[w], lw[w], 0x05040100u); // elem 2w
        u32 po = __builtin_amdgcn_perm(hw[w], lw[w], 0x07060302u); // elem 2w+1
        int c0 = sc8 + 2*w;
        kTp[c0*68 + (r ^ kx)]     = pe;
        kTp[(c0+1)*68 + (r ^ kx)] = po;
      }
    }
    *(float4*)&v_s[vr*36 + vc4] = vreg;
    if (tid < 256) dec_s[tid] = dreg;

    // ---- prefetch stage data n+1 (regs free after writes above) ----
    if (n < 63){
#pragma unroll
      for (int it = 0; it < 2; it++){
        int r = it*32 + sr0;
        size_t g = (rowbase + tbase + 64 + r) * 2048 + (size_t)h*128 + sc8;
        kuh[it] = *(const uint4*)&kh[g];
        kul[it] = *(const uint4*)&kl[g];
      }
      { size_t g = (rowbase + tbase + 64 + vr) * 2048 + (size_t)h*128 + v0 + vc4;
        vreg = *(const float4*)&vo[g]; }
      if (tid < 256) dreg = dsrc[doff + tbase + 64];
    }

    // ---- e = k @ W^T (A from regs, W from LDS), 3-term ----
    f32x4 eacc = {};
#pragma unroll
    for (int ks = 0; ks < 4; ks++){
      bf16x8 bh_ = *(const bf16x8*)&Wh[(jh*16 + rw)*WSTR + ks*32 + kq];
      bf16x8 bl_ = *(const bf16x8*)&Wl[(jh*16 + rw)*WSTR + ks*32 + kq];
      f32x4 t = mfma16(kal[ks], bh_, eacc);
      t = mfma16(kah[ks], bl_, t);
      eacc = mfma16(kah[ks], bh_, t);
    }
    // prefetch e-A n+1
    if (n < 63){
#pragma unroll
      for (int ks = 0; ks < 4; ks++){
        kah[ks] = *(const bf16x8*)(kh + fragA + nx + ks*32 + kq);
        kal[ks] = *(const bf16x8*)(kl + fragA + nx + ks*32 + kq);
      }
    }
    // ---- qk (2 tiles, B from regs) and zq ----
    f32x4 qkacc[2] = {};
    f32x4 zqacc = {};
#pragma unroll
    for (int ks = 0; ks < 4; ks++){
#pragma unroll
      for (int j2 = 0; j2 < 2; j2++){
        f32x4 t = mfma16(qcl[ks], kbh[j2][ks], qkacc[j2]);
        t = mfma16(qch[ks], kbl[j2][ks], t);
        qkacc[j2] = mfma16(qch[ks], kbh[j2][ks], t);
      }
      bf16x8 wh_ = *(const bf16x8*)&Wh[(jh*16 + rw)*WSTR + ks*32 + kq];
      bf16x8 wl_ = *(const bf16x8*)&Wl[(jh*16 + rw)*WSTR + ks*32 + kq];
      f32x4 t = mfma16(qcl[ks], wh_, zqacc);
      t = mfma16(qch[ks], wl_, t);
      zqacc = mfma16(qch[ks], wh_, t);
    }
    // prefetch q / qk-B n+1
    if (n < 63){
#pragma unroll
      for (int ks = 0; ks < 4; ks++){
        qch[ks] = *(const bf16x8*)(qh + fragA + nx + ks*32 + kq);
        qcl[ks] = *(const bf16x8*)(ql + fragA + nx + ks*32 + kq);
        kbh[0][ks] = *(const bf16x8*)(kh + fragB0 + nx + ks*32 + kq);
        kbl[0][ks] = *(const bf16x8*)(kl + fragB0 + nx + ks*32 + kq);
        kbh[1][ks] = *(const bf16x8*)(kh + fragB1 + nx + ks*32 + kq);
        kbl[1][ks] = *(const bf16x8*)(kl + fragB1 + nx + ks*32 + kq);
      }
    }
    __syncthreads();                    // bar1: kT/v/dec visible; W reads done

    // ---- e finalize: e -= v, pack (h<<16|l), b64 stores to epk/ewpk ----
    {
      const int vv = jh*16 + ccol;
      const int t0 = tw*16 + cquad*4;
      u32 pe[4], pw[4];
#pragma unroll
      for (int r = 0; r < 4; r++){
        int t = t0 + r;
        float e = eacc[r] - v_s[t*36 + vv];
        u16b h1, l1; split2(e, h1, l1);
        pe[r] = ((u32)h1 << 16) | l1;
        float ew = e * dec_s[128 + t];
        u16b h2, l2; split2(ew, h2, l2);
        pw[r] = ((u32)h2 << 16) | l2;
      }
      const int tS = t0 ^ ((vv & 7) << 3);
      uint2 w0; w0.x = pe[0]; w0.y = pe[1];
      uint2 w1; w1.x = pe[2]; w1.y = pe[3];
      *(uint2*)&epk[vv*68 + tS]     = w0;
      *(uint2*)&epk[vv*68 + tS + 2] = w1;
      uint2 w2; w2.x = pw[0]; w2.y = pw[1];
      uint2 w3; w3.x = pw[2]; w3.y = pw[3];
      *(uint2*)&ewpk[vv*68 + tS]     = w2;
      *(uint2*)&ewpk[vv*68 + tS + 2] = w3;
    }
    // ---- S = qk * beta * th[j], tril, swizzled split store ----
#pragma unroll
    for (int j2 = 0; j2 < 2; j2++)
#pragma unroll
      for (int r = 0; r < 4; r++){
        int t  = tw*16 + cquad*4 + r;
        int jj = (jh*2 + j2)*16 + ccol;
        float s = 0.f;
        if (jj <= t)
          s = qkacc[j2][r] * __expf(fminf(dec_s[t] - dec_s[jj], 0.f)) * dec_s[192 + jj];
        u16b h1, l1; split2(s, h1, l1);
        int jjs = jj ^ (((t >> 2) & 7) << 3);
        Sh_s[t*72 + jjs] = h1;  Sl_s[t*72 + jjs] = l1;
      }
    __syncthreads();                    // bar2: e/ew/S visible to all waves

    // ---- Se = S @ e (rows tw, cols jh-half) ----
    f32x4 seacc = {};
#pragma unroll
    for (int ks2 = 0; ks2 < 2; ks2++){
      const int srow = tw*16 + rw;
      const int scol2 = (ks2*32 + kq) ^ (((srow >> 2) & 7) << 3);
      bf16x8 ah = *(const bf16x8*)&Sh_s[srow*72 + scol2];
      bf16x8 al = *(const bf16x8*)&Sl_s[srow*72 + scol2];
      const int erow = jh*16 + rw;
      const int ecol = (ks2*32 + kq) ^ ((erow & 7) << 3);
      bf16x8 bh_, bl_;
      unpack8(&epk[erow*68 + ecol], bh_, bl_);
      f32x4 t = mfma16(al, bh_, seacc);
      t = mfma16(ah, bl_, t);
      seacc = mfma16(ah, bh_, t);
    }
    // ---- z -> vo in place (stores are fire-and-forget) ----
#pragma unroll
    for (int r = 0; r < 4; r++){
      int t  = tw*16 + cquad*4 + r;
      int vv = jh*16 + ccol;
      float z = dec_s[64 + t]*zqacc[r] - seacc[r];
      vo[((rowbase + tbase + t)*16 + h)*128 + v0 + vv] = z;
    }
    // ---- dw: A = ew^T rows (mi), B = packed kT rows (kcol) ----
    f32x4 dwacc[2] = {};
    const int kcol = wid*16 + rw;
    const int kx2  = ((kcol >> 3) & 3) << 3;
#pragma unroll
    for (int ks2 = 0; ks2 < 2; ks2++){
      bf16x8 bh_, bl_;
      unpack8(&kTp[kcol*68 + ((ks2*32 + kq) ^ kx2)], bh_, bl_);
#pragma unroll
      for (int mi = 0; mi < 2; mi++){
        const int arow = mi*16 + rw;
        const int acol = (ks2*32 + kq) ^ ((arow & 7) << 3);
        bf16x8 amh, aml;
        unpack8(&ewpk[arow*68 + acol], amh, aml);
        f32x4 t = mfma16(aml, bh_, dwacc[mi]);
        t = mfma16(amh, bl_, t);
        dwacc[mi] = mfma16(amh, bh_, t);
      }
    }
    // ---- W <- W*elt63 - dw (8 disjoint elems/lane) ----
    float dfac = dec_s[64 + 63];
#pragma unroll
    for (int mi = 0; mi < 2; mi++)
#pragma unroll
      for (int r = 0; r < 4; r++){
        int vv = mi*16 + cquad*4 + r;
        int kk = wid*16 + ccol;
        int idx = vv*WSTR + kk;
        float w = bf2f(Wh[idx]) + bf2f(Wl[idx]);
        w = w*dfac - dwacc[mi][r];
        u16b h1, l1; split2(w, h1, l1);
        Wh[idx] = h1; Wl[idx] = l1;
      }
  }
}
#undef WSTR

// ---------------------------------------------------------------------------
// Gated RMSNorm, f32 in -> split bf16 out.
// ---------------------------------------------------------------------------
__global__ __launch_bounds__(256) void norm_kernel(
    const float* __restrict__ outs, const float* __restrict__ g,
    const float* __restrict__ nw, u16b* __restrict__ ogh, u16b* __restrict__ ogl)
{
  const int bt = blockIdx.x;
  const int tid = threadIdx.x;
  size_t base = (size_t)bt*2048 + (size_t)tid*8;
  float4 x0 = *(const float4*)(outs + base);
  float4 x1 = *(const float4*)(outs + base + 4);
  float x[8] = {x0.x,x0.y,x0.z,x0.w,x1.x,x1.y,x1.z,x1.w};
  float ss = 0.f;
#pragma unroll
  for (int i = 0; i < 8; i++) ss += x[i]*x[i];
#pragma unroll
  for (int off = 1; off < 16; off <<= 1) ss += __shfl_xor(ss, off);  // 16-lane head
  float rs = rsqrtf(ss*(1.f/128.f) + 1e-5f);
  float4 g0 = *(const float4*)(g + base);
  float4 g1 = *(const float4*)(g + base + 4);
  float gg[8] = {g0.x,g0.y,g0.z,g0.w,g1.x,g1.y,g1.z,g1.w};
  int nwb = (tid & 15)*8;
  u16b oh[8], ol[8];
#pragma unroll
  for (int i = 0; i < 8; i++){
    float sig = 1.f / (1.f + __expf(-gg[i]));
    float v = x[i]*rs*nw[nwb+i]*gg[i]*sig;
    split2(v, oh[i], ol[i]);
  }
  *(uint4*)(ogh + base) = *(const uint4*)oh;
  *(uint4*)(ogl + base) = *(const uint4*)ol;
}

// ---------------------------------------------------------------------------
extern "C" void kernel_launch(void* const* d_in, const int* in_sizes, int n_in,
                              void* d_out, int out_size, void* d_ws, size_t ws_size,
                              hipStream_t stream)
{
  (void)in_sizes; (void)n_in; (void)out_size; (void)ws_size;
  const float* x    = (const float*)d_in[0];
  const float* Wq   = (const float*)d_in[1];
  const float* Wk   = (const float*)d_in[2];
  const float* Wv   = (const float*)d_in[3];
  const float* Weta = (const float*)d_in[4];
  const float* Wth  = (const float*)d_in[5];
  const float* Wg   = (const float*)d_in[6];
  const float* nw   = (const float*)d_in[7];
  const float* Wo   = (const float*)d_in[8];
  float* out = (float*)d_out;

  const size_t SZ = (size_t)8192*2048;      // activation elems
  const size_t WZ = (size_t)2048*2048;      // weight elems
  const size_t DS = (size_t)2*16*4096;      // decay arrays (B,H,T)
  u16b* ws = (u16b*)d_ws;
  u16b* qhb = ws;            u16b* qlb = qhb + SZ;
  u16b* khb = qlb + SZ;      u16b* klb = khb + SZ;
  float* vob  = (float*)(klb + SZ);         // v, then outs in place
  float* etab = vob + SZ;
  float* thb  = etab + DS;
  float* lecb = thb  + DS;
  float* eltb = lecb + DS;
  float* wtb  = eltb + DS;
  float* gfb  = (float*)khb;                // g f32 after scan (spans kh+kl)
  u16b* ogh = qhb; u16b* ogl = qlb;         // og reuses q slot

  // x split lives in d_out (exactly 2*SZ u16 = out_size); dead before final gemm
  u16b* xh = (u16b*)d_out;   u16b* xl = xh + SZ;
  // weight splits float through dead regions (16.8 MB each, lifetimes checked):
  u16b* wsQh = khb;        u16b* wsQl = khb + WZ;   // dead when gemm k writes kh
  u16b* wsKh = (u16b*)vob; u16b* wsKl = wsKh + WZ;  // dead when gemm v writes vob
  u16b* wsGh = qhb;        u16b* wsGl = qhb + WZ;   // q dead after scan; dead before norm
  u16b* wsOh = khb;        u16b* wsOl = khb + WZ;   // gfb dead after norm

  dim3 gg(1024);
  split_kernel<<<8192, 256, 0, stream>>>(x, xh, xl, (int)(SZ/8));
  etatheta_kernel<<<8192, 256, 0, stream>>>(x, Weta, Wth, etab, thb);
  decay_kernel<<<dim3(32,64), 64, 0, stream>>>(etab, thb, lecb, eltb, wtb);

  split_kernel<<<2048, 256, 0, stream>>>(Wq, wsQh, wsQl, (int)(WZ/8));
  gemm3v<1,0><<<gg, 256, 0, stream>>>(xh, xl, wsQh, wsQl, nullptr,
                                      qhb, qlb, nullptr,
                                      8192, 2048, 2048, 0.08838834764831843f);
  split_kernel<<<2048, 256, 0, stream>>>(Wk, wsKh, wsKl, (int)(WZ/8));
  gemm3v<1,0><<<gg, 256, 0, stream>>>(xh, xl, wsKh, wsKl, nullptr,
                                      khb, klb, nullptr,
                                      8192, 2048, 2048, 1.f);
  gemm3v<0,1><<<gg, 256, 0, stream>>>(xh, xl, nullptr, nullptr, Wv,
                                      nullptr, nullptr, vob,
                                      8192, 2048, 2048, 1.f);
  scan_kernel<<<dim3(32,4), 512, 0, stream>>>(qhb, qlb, khb, klb,
                                              lecb, eltb, wtb, thb, vob);
  split_kernel<<<2048, 256, 0, stream>>>(Wg, wsGh, wsGl, (int)(WZ/8));
  gemm3v<1,1><<<gg, 256, 0, stream>>>(xh, xl, wsGh, wsGl, nullptr,
                                      nullptr, nullptr, gfb,
                                      8192, 2048, 2048, 1.f);
  norm_kernel<<<8192, 256, 0, stream>>>(vob, gfb, nw, ogh, ogl);
  split_kernel<<<2048, 256, 0, stream>>>(Wo, wsOh, wsOl, (int)(WZ/8));
  gemm3v<1,1><<<gg, 256, 0, stream>>>(ogh, ogl, wsOh, wsOl, nullptr,
                                      nullptr, nullptr, out,
                                      8192, 2048, 2048, 1.f);
}

// Round 6
// 1768.014 us; speedup vs baseline: 1.1452x; 1.1452x over previous
//
#include <hip/hip_runtime.h>
#include <cstdint>
#include <cstddef>

// ---------------------------------------------------------------------------
// LinearSGD fused pipeline for MI355X (gfx950).  ALL I/O is float32.
// Precision: split-bf16 (hi+lo) at every MFMA (truncation split:
//   hi = trunc_bf16(x), lo = trunc_bf16(x - hi), |err| <= 2^-16 |x|),
//   A@B ~= Ah@Bh + Ah@Bl + Al@Bh  (3-term, f32 accum).
// Round 6: recombine best-measured kernels.
//   - gemm3v: round-5 2-phase dbuf (counted vmcnt(8) + raw s_barrier),
//     measured ~-40 us aggregate vs 1-phase.
//   - scan: REVERTED to round-4 v3 (324 us measured).  Round-5's
//     "k-fragments direct from global" regressed to 618 us: per-wave
//     redundant scattered loads + __syncthreads vmcnt(0) drain killed the
//     prefetch (documented HIP-compiler barrier-drain behavior).
// ---------------------------------------------------------------------------

typedef unsigned short u16b;
typedef uint32_t u32;
typedef __attribute__((ext_vector_type(8))) __bf16 bf16x8;
typedef __attribute__((ext_vector_type(4))) float  f32x4;

__device__ __forceinline__ float bf2f(u16b v){
  union { float f; uint32_t u; } x; x.u = ((uint32_t)v) << 16; return x.f;
}
// truncation-based split: cheap (no rounding chains), hi+lo ~ f to 2^-16
__device__ __forceinline__ void split2(float f, u16b& h, u16b& l){
  uint32_t u = __float_as_uint(f);
  float hf = __uint_as_float(u & 0xFFFF0000u);
  h = (u16b)(u >> 16);
  l = (u16b)(__float_as_uint(f - hf) >> 16);
}
__device__ __forceinline__ f32x4 mfma16(bf16x8 a, bf16x8 b, f32x4 c){
  return __builtin_amdgcn_mfma_f32_16x16x32_bf16(a, b, c, 0, 0, 0);
}
// async global->LDS, 16B per lane (dest = wave-uniform base + lane*16)
__device__ __forceinline__ void gl16(const void* g, void* l){
  __builtin_amdgcn_global_load_lds(
      (const __attribute__((address_space(1))) u32*)g,
      (__attribute__((address_space(3))) u32*)l, 16, 0, 0);
}
// swizzled index for the scan's [64][128]-u16 k tiles (bank-conflict fix)
__device__ __forceinline__ int ksw(int r, int c){
  return r*128 + (c ^ ((r & 7) << 3));
}
// unpack 8 packed u32 (h<<16|l) -> hi bf16x8 + lo bf16x8 via v_perm
__device__ __forceinline__ void unpack8(const u32* p, bf16x8& hv, bf16x8& lv){
  uint4 P0 = *(const uint4*)p;
  uint4 P1 = *(const uint4*)(p + 4);
  union { u32 w[4]; bf16x8 v; } H, L;
  H.w[0] = __builtin_amdgcn_perm(P0.y, P0.x, 0x07060302u);
  H.w[1] = __builtin_amdgcn_perm(P0.w, P0.z, 0x07060302u);
  H.w[2] = __builtin_amdgcn_perm(P1.y, P1.x, 0x07060302u);
  H.w[3] = __builtin_amdgcn_perm(P1.w, P1.z, 0x07060302u);
  L.w[0] = __builtin_amdgcn_perm(P0.y, P0.x, 0x05040100u);
  L.w[1] = __builtin_amdgcn_perm(P0.w, P0.z, 0x05040100u);
  L.w[2] = __builtin_amdgcn_perm(P1.y, P1.x, 0x05040100u);
  L.w[3] = __builtin_amdgcn_perm(P1.w, P1.z, 0x05040100u);
  hv = H.v; lv = L.v;
}

// ---------------------------------------------------------------------------
// f32 -> (hi,lo) bf16 split, 8 elems/thread, fully coalesced.
// ---------------------------------------------------------------------------
__global__ __launch_bounds__(256) void split_kernel(
    const float* __restrict__ src, u16b* __restrict__ dh, u16b* __restrict__ dl,
    int n8)
{
  int i = blockIdx.x*256 + threadIdx.x;
  if (i >= n8) return;
  const float4* s4 = (const float4*)src;
  float4 a = s4[2*(size_t)i], b = s4[2*(size_t)i + 1];
  float f[8] = {a.x,a.y,a.z,a.w,b.x,b.y,b.z,b.w};
  u16b h[8], l[8];
#pragma unroll
  for (int j = 0; j < 8; j++) split2(f[j], h[j], l[j]);
  *(uint4*)(dh + (size_t)i*8) = *(const uint4*)h;
  *(uint4*)(dl + (size_t)i*8) = *(const uint4*)l;
}

// ---------------------------------------------------------------------------
// Split GEMM v3: C[M,N] = (Ah+Al)[M,Kd] @ (Bh+Bl)[N,Kd]^T, 3-term MFMA.
// BMODE 1: 2-phase dbuf (counted vmcnt(8) + raw barriers, loads in flight
// across barriers).  BMODE 0: B f32 split in-kernel, old 1-phase loop.
// 128x128 tile, 4 waves 2x2, BK=32.  T2 XOR-swizzled [.][32] tiles
// (pre-swizzled global source col; reads XOR the slot).  Coalesced
// LDS-bounce epilogue.  OUTMODE 0: (Ch,Cl) split; 1: Cf f32.
// ---------------------------------------------------------------------------
template<int BMODE, int OUTMODE>
__global__ __launch_bounds__(256) void gemm3v(
    const u16b* __restrict__ Ah, const u16b* __restrict__ Al,
    const u16b* __restrict__ Bh, const u16b* __restrict__ Bl,
    const float* __restrict__ Bf,
    u16b* __restrict__ Ch, u16b* __restrict__ Cl, float* __restrict__ Cf,
    int M, int N, int Kd, float alpha)
{
  (void)M;
  __shared__ __align__(16) u16b smem[32768];   // 64 KB: 2 staging bufs / bounce

  // XCD-aware bijective swizzle (gridDim.x % 8 == 0)
  const int cpx = gridDim.x >> 3;
  const int flat = blockIdx.x;
  const int swz = (flat & 7) * cpx + (flat >> 3);
  const int nb = N >> 7;
  const int m0 = (swz / nb) * 128;
  const int n0 = (swz % nb) * 128;

  const int tid  = threadIdx.x;
  const int wid  = tid >> 6;
  const int lane = tid & 63;
  const int wm = (wid & 1) * 64;
  const int wn = (wid >> 1) * 64;
  const int rw = lane & 15;
  const int kq = (lane >> 4) * 8;
  const int sx = ((rw >> 1) & 3) << 3;   // fragment-read swizzle XOR

  const int srow = tid >> 2;
  const int scol = ((tid & 3) * 8) ^ (((tid >> 3) & 3) << 3);
  const u16b* gA0 = Ah + (size_t)(m0 + srow)*Kd + scol;
  const u16b* gA1 = gA0 + (size_t)64*Kd;
  const u16b* gAl0 = Al + (size_t)(m0 + srow)*Kd + scol;
  const u16b* gAl1 = gAl0 + (size_t)64*Kd;

  f32x4 acc[4][4] = {};

  if constexpr (BMODE == 1){
    const u16b* gB0  = Bh + (size_t)(n0 + srow)*Kd + scol;
    const u16b* gB1  = gB0 + (size_t)64*Kd;
    const u16b* gBl0 = Bl + (size_t)(n0 + srow)*Kd + scol;
    const u16b* gBl1 = gBl0 + (size_t)64*Kd;

    auto stage = [&](int buf, int k0){
      u16b* base = smem + buf*16384;
      gl16(gA0  + k0, base + tid*8);
      gl16(gA1  + k0, base + 2048  + tid*8);
      gl16(gAl0 + k0, base + 4096  + tid*8);
      gl16(gAl1 + k0, base + 6144  + tid*8);
      gl16(gB0  + k0, base + 8192  + tid*8);
      gl16(gB1  + k0, base + 10240 + tid*8);
      gl16(gBl0 + k0, base + 12288 + tid*8);
      gl16(gBl1 + k0, base + 14336 + tid*8);
    };

    stage(0, 0);
    int cur = 0;
    for (int k0 = 0; k0 < Kd; k0 += 32, cur ^= 1){
      const u16b* Ahs = smem + cur*16384;
      const u16b* Als = Ahs + 4096;
      const u16b* Bhs = Ahs + 8192;
      const u16b* Bls = Ahs + 12288;
      if (k0 + 32 < Kd){
        stage(cur ^ 1, k0 + 32);              // next tile in flight
        asm volatile("s_waitcnt vmcnt(8)" ::: "memory");  // cur landed
      } else {
        asm volatile("s_waitcnt vmcnt(0)" ::: "memory");
      }
      __builtin_amdgcn_s_barrier();           // all waves: cur visible

      bf16x8 afh[4], afl[4], bfh[4], bfl[4];
#pragma unroll
      for (int i = 0; i < 4; i++){
        afh[i] = *(const bf16x8*)&Ahs[(wm + i*16 + rw)*32 + (kq ^ sx)];
        afl[i] = *(const bf16x8*)&Als[(wm + i*16 + rw)*32 + (kq ^ sx)];
      }
#pragma unroll
      for (int j = 0; j < 4; j++){
        bfh[j] = *(const bf16x8*)&Bhs[(wn + j*16 + rw)*32 + (kq ^ sx)];
        bfl[j] = *(const bf16x8*)&Bls[(wn + j*16 + rw)*32 + (kq ^ sx)];
      }
#pragma unroll
      for (int i = 0; i < 4; i++)
#pragma unroll
        for (int j = 0; j < 4; j++){
          f32x4 t = mfma16(afl[i], bfh[j], acc[i][j]);
          t = mfma16(afh[i], bfl[j], t);
          acc[i][j] = mfma16(afh[i], bfh[j], t);
        }
      __builtin_amdgcn_s_barrier();           // cur reads done -> reusable
    }
  } else {
    // ---- old 1-phase loop, B split in-kernel (v-projection only) ----
    u16b* Ahs = smem;
    u16b* Als = smem + 4096;
    u16b* Bhs = smem + 8192;
    u16b* Bls = smem + 12288;
    for (int k0 = 0; k0 < Kd; k0 += 32){
      float4 fb[4];
#pragma unroll
      for (int it = 0; it < 4; it++){
        int idx = it*256 + tid;
        int rr = idx >> 3, c4 = (idx & 7) * 4;
        fb[it] = *(const float4*)(Bf + (size_t)(n0 + rr) * Kd + k0 + c4);
      }
      __syncthreads();                     // prev-iter LDS reads done
      gl16(gA0  + k0, Ahs + tid*8);
      gl16(gA1  + k0, Ahs + 2048 + tid*8);
      gl16(gAl0 + k0, Als + tid*8);
      gl16(gAl1 + k0, Als + 2048 + tid*8);
#pragma unroll
      for (int it = 0; it < 4; it++){
        int idx = it*256 + tid;
        int rr = idx >> 3, c4 = (idx & 7) * 4;
        int cs = c4 ^ (((rr >> 1) & 3) << 3);   // swizzled store col
        float f[4] = {fb[it].x, fb[it].y, fb[it].z, fb[it].w};
        u16b h[4], l[4];
#pragma unroll
        for (int j = 0; j < 4; j++) split2(f[j], h[j], l[j]);
        *(uint2*)&Bhs[rr*32 + cs] = *(const uint2*)h;
        *(uint2*)&Bls[rr*32 + cs] = *(const uint2*)l;
      }
      __syncthreads();                     // tile ready

      bf16x8 afh[4], afl[4], bfh[4], bfl[4];
#pragma unroll
      for (int i = 0; i < 4; i++){
        afh[i] = *(const bf16x8*)&Ahs[(wm + i*16 + rw)*32 + (kq ^ sx)];
        afl[i] = *(const bf16x8*)&Als[(wm + i*16 + rw)*32 + (kq ^ sx)];
      }
#pragma unroll
      for (int j = 0; j < 4; j++){
        bfh[j] = *(const bf16x8*)&Bhs[(wn + j*16 + rw)*32 + (kq ^ sx)];
        bfl[j] = *(const bf16x8*)&Bls[(wn + j*16 + rw)*32 + (kq ^ sx)];
      }
#pragma unroll
      for (int i = 0; i < 4; i++)
#pragma unroll
        for (int j = 0; j < 4; j++){
          f32x4 t = mfma16(afl[i], bfh[j], acc[i][j]);
          t = mfma16(afh[i], bfl[j], t);
          acc[i][j] = mfma16(afh[i], bfh[j], t);
        }
    }
  }

  // ---- epilogue: LDS bounce for coalesced stores ----
  float* Bnc = (float*)smem;             // 32*132*4 = 16896 B (fits buf0)
  const int ccol  = lane & 15;
  const int cquad = lane >> 4;
  const int brb = ((wid & 1) << 4) + cquad*4;
  const int br2 = tid >> 3, c0 = (tid & 7) * 16;
#pragma unroll
  for (int i = 0; i < 4; i++){
    __syncthreads();
#pragma unroll
    for (int j = 0; j < 4; j++)
#pragma unroll
      for (int r = 0; r < 4; r++)
        Bnc[(brb + r)*132 + wn + j*16 + ccol] = acc[i][j][r];
    __syncthreads();
    const int rowg = m0 + ((br2 >> 4) << 6) + i*16 + (br2 & 15);
    float4 x0 = *(const float4*)&Bnc[br2*132 + c0];
    float4 x1 = *(const float4*)&Bnc[br2*132 + c0 + 4];
    float4 x2 = *(const float4*)&Bnc[br2*132 + c0 + 8];
    float4 x3 = *(const float4*)&Bnc[br2*132 + c0 + 12];
    float v[16] = {x0.x,x0.y,x0.z,x0.w, x1.x,x1.y,x1.z,x1.w,
                   x2.x,x2.y,x2.z,x2.w, x3.x,x3.y,x3.z,x3.w};
#pragma unroll
    for (int e = 0; e < 16; e++) v[e] *= alpha;
    if constexpr (OUTMODE == 0){
      u16b h[16], l[16];
#pragma unroll
      for (int e = 0; e < 16; e++) split2(v[e], h[e], l[e]);
      size_t off = (size_t)rowg * N + n0 + c0;
      *(uint4*)(Ch + off)     = *(const uint4*)&h[0];
      *(uint4*)(Ch + off + 8) = *(const uint4*)&h[8];
      *(uint4*)(Cl + off)     = *(const uint4*)&l[0];
      *(uint4*)(Cl + off + 8) = *(const uint4*)&l[8];
    } else {
      size_t off = (size_t)rowg * N + n0 + c0;
      *(float4*)(Cf + off)      = *(const float4*)&v[0];
      *(float4*)(Cf + off + 4)  = *(const float4*)&v[4];
      *(float4*)(Cf + off + 8)  = *(const float4*)&v[8];
      *(float4*)(Cf + off + 12) = *(const float4*)&v[12];
    }
  }
}

// ---------------------------------------------------------------------------
// eta/theta skinny projection (pure f32): per (b,t) row, 32 dots of 2048.
// ---------------------------------------------------------------------------
__global__ __launch_bounds__(256) void etatheta_kernel(
    const float* __restrict__ x, const float* __restrict__ Weta,
    const float* __restrict__ Wtheta, float* __restrict__ eta, float* __restrict__ theta)
{
  __shared__ float xr[2048];
  const int bt = blockIdx.x;
  const int b = bt >> 12, t = bt & 4095;
  const float* xp = x + (size_t)bt * 2048;
  for (int i = threadIdx.x; i < 2048; i += 256) xr[i] = xp[i];
  __syncthreads();
  const int wid = threadIdx.x >> 6, lane = threadIdx.x & 63;
  for (int oi = 0; oi < 8; oi++){
    int og = wid*8 + oi;
    const float* wrow = (og < 16) ? (Weta + (size_t)og*2048)
                                  : (Wtheta + (size_t)(og-16)*2048);
    float acc = 0.f;
    for (int d = lane; d < 2048; d += 64) acc += xr[d] * wrow[d];
#pragma unroll
    for (int off = 32; off; off >>= 1) acc += __shfl_down(acc, off);
    if (lane == 0){
      float s = 1.f / (1.f + expf(-acc));
      if (og < 16) eta  [((size_t)(b*16 + og     ))*4096 + t] = s;
      else         theta[((size_t)(b*16 + og - 16))*4096 + t] = 0.1f * s;
    }
  }
}

// ---------------------------------------------------------------------------
// Decay precompute: per (bh, chunk) of 64 t: lec = cumsum(log eta),
// elt = exp(lec), wt = exp(lec63 - lec) * theta.
// ---------------------------------------------------------------------------
__global__ __launch_bounds__(64) void decay_kernel(
    const float* __restrict__ eta, const float* __restrict__ th,
    float* __restrict__ lecb, float* __restrict__ eltb, float* __restrict__ wtb)
{
  const int bh = blockIdx.x, n = blockIdx.y, lane = threadIdx.x;
  size_t idx = (size_t)bh*4096 + n*64 + lane;
  float cum = logf(fmaxf(eta[idx], 1e-8f));
#pragma unroll
  for (int off = 1; off < 64; off <<= 1){
    float o = __shfl_up(cum, off);
    if (lane >= off) cum += o;
  }
  float lec63 = __shfl(cum, 63);
  lecb[idx] = cum;
  eltb[idx] = expf(cum);
  wtb[idx]  = expf(lec63 - cum) * th[idx];
}

// ---------------------------------------------------------------------------
// Chunk scan v3 (round-4 version, 324 us measured): packed-u32 kT/e/ew,
// S-store XOR swizzle, k/v/dec/q register prefetch.
// Grid (B*H, V/32), block 512 = 8 waves (tw = wid&3, jh = wid>>2).
// ---------------------------------------------------------------------------
#define WSTR 136
__global__ __launch_bounds__(512) void scan_kernel(
    const u16b* __restrict__ qh, const u16b* __restrict__ ql,
    const u16b* __restrict__ kh, const u16b* __restrict__ kl,
    const float* __restrict__ lecb, const float* __restrict__ eltb,
    const float* __restrict__ wtb,  const float* __restrict__ thb,
    float* vo)                                     // v in, outs out (aliased)
{
  __shared__ u16b kh_s[64*128], kl_s[64*128];
  __shared__ u32  kTp[128*68];                 // packed kT (h<<16|l), XOR r-blocks
  __shared__ u16b Wh[32*WSTR], Wl[32*WSTR];
  __shared__ u32  epk [32*68];                 // packed e^T [vv][t], XOR t-blocks
  __shared__ u32  ewpk[32*68];                 // packed (wt*e)^T
  __shared__ u16b Sh_s[64*72], Sl_s[64*72];    // XOR-swizzled cols
  __shared__ float v_s[64*36];
  __shared__ float dec_s[4*64];    // [0]=lec [1]=elt [2]=wt [3]=th

  const int bh = blockIdx.x;
  const int b = bh >> 4, h = bh & 15;
  const int v0 = blockIdx.y * 32;
  const int tid  = threadIdx.x;
  const int wid  = tid >> 6;       // 0..7
  const int tw   = wid & 3;        // t 16-row block
  const int jh   = wid >> 2;       // j/v 16-col half
  const int lane = tid & 63;
  const int rw = lane & 15;
  const int kq = (lane >> 4) * 8;
  const int ccol  = lane & 15;
  const int cquad = lane >> 4;

  for (int i = tid; i < 32*WSTR; i += 512){ Wh[i] = 0; Wl[i] = 0; }

  const size_t rowbase = (size_t)b * 4096;
  const size_t decbase = (size_t)bh * 4096;
  const int sr0 = tid >> 4;             // k staging row (it=0), +32 for it=1
  const int sc8 = (tid & 15) * 8;       // k staging col
  const int vr  = tid >> 3;             // v staging row
  const int vc4 = (tid & 7) * 4;        // v staging col
  const float* dsrc = (tid < 64) ? lecb : (tid < 128) ? eltb
                     : (tid < 192) ? wtb : thb;
  const size_t doff = decbase + (tid & 63);

  // ---- prefetch registers ----
  uint4 kuh[2], kul[2];
  float4 vreg;
  float dreg = 0.f;
  bf16x8 qch[4], qcl[4];

  // ---- prologue: load chunk 0 ----
  {
#pragma unroll
    for (int it = 0; it < 2; it++){
      int r = it*32 + sr0;
      size_t g = (rowbase + r) * 2048 + (size_t)h*128 + sc8;
      kuh[it] = *(const uint4*)&kh[g];
      kul[it] = *(const uint4*)&kl[g];
    }
    { size_t g = (rowbase + vr) * 2048 + (size_t)h*128 + v0 + vc4;
      vreg = *(const float4*)&vo[g]; }
    dreg = dsrc[doff];
    const size_t qg0 = (rowbase + tw*16 + rw) * 2048 + (size_t)h*128;
#pragma unroll
    for (int ks = 0; ks < 4; ks++){
      qch[ks] = *(const bf16x8*)(qh + qg0 + ks*32 + kq);
      qcl[ks] = *(const bf16x8*)(ql + qg0 + ks*32 + kq);
    }
  }

  for (int n = 0; n < 64; n++){
    const int tbase = n * 64;
    __syncthreads();                    // prev chunk LDS reads + W update done

    // ---- write staged k regs: rows (swizzled) + packed kT scatter ----
#pragma unroll
    for (int it = 0; it < 2; it++){
      int r = it*32 + sr0;
      *(uint4*)&kh_s[ksw(r, sc8)] = kuh[it];
      *(uint4*)&kl_s[ksw(r, sc8)] = kul[it];
      const u32* hw = (const u32*)&kuh[it];
      const u32* lw = (const u32*)&kul[it];
      const int kx = ((sc8 >> 3) & 3) << 3;     // layout XOR for this lane's cols
#pragma unroll
      for (int w = 0; w < 4; w++){
        u32 pe = __builtin_amdgcn_perm(hw[w], lw[w], 0x05040100u); // elem 2w
        u32 po = __builtin_amdgcn_perm(hw[w], lw[w], 0x07060302u); // elem 2w+1
        int c0 = sc8 + 2*w;
        kTp[c0*68 + (r ^ kx)]     = pe;
        kTp[(c0+1)*68 + (r ^ kx)] = po;
      }
    }
    *(float4*)&v_s[vr*36 + vc4] = vreg;
    if (tid < 256) dec_s[tid] = dreg;
    __syncthreads();                    // LDS ready

    // ---- prefetch k/v/dec for chunk n+1 (hidden under compute) ----
    if (n < 63){
      const int tb2 = tbase + 64;
#pragma unroll
      for (int it = 0; it < 2; it++){
        int r = it*32 + sr0;
        size_t g = (rowbase + tb2 + r) * 2048 + (size_t)h*128 + sc8;
        kuh[it] = *(const uint4*)&kh[g];
        kul[it] = *(const uint4*)&kl[g];
      }
      { size_t g = (rowbase + tb2 + vr) * 2048 + (size_t)h*128 + v0 + vc4;
        vreg = *(const float4*)&vo[g]; }
      dreg = dsrc[doff + tb2];
    }

    // ---- e = k @ W^T (rows tw, cols jh-half), 3-term ----
    f32x4 eacc = {};
#pragma unroll
    for (int ks = 0; ks < 4; ks++){
      bf16x8 ah  = *(const bf16x8*)&kh_s[ksw(tw*16 + rw, ks*32 + kq)];
      bf16x8 al  = *(const bf16x8*)&kl_s[ksw(tw*16 + rw, ks*32 + kq)];
      bf16x8 bh_ = *(const bf16x8*)&Wh[(jh*16 + rw)*WSTR + ks*32 + kq];
      bf16x8 bl_ = *(const bf16x8*)&Wl[(jh*16 + rw)*WSTR + ks*32 + kq];
      f32x4 t = mfma16(al, bh_, eacc);
      t = mfma16(ah, bl_, t);
      eacc = mfma16(ah, bh_, t);
    }
    // ---- qk (2 tiles: j4 = jh*2 + j2) and zq (1 tile) ----
    f32x4 qkacc[2] = {};
    f32x4 zqacc = {};
#pragma unroll
    for (int ks = 0; ks < 4; ks++){
#pragma unroll
      for (int j2 = 0; j2 < 2; j2++){
        int j4 = jh*2 + j2;
        bf16x8 bh_ = *(const bf16x8*)&kh_s[ksw(j4*16 + rw, ks*32 + kq)];
        bf16x8 bl_ = *(const bf16x8*)&kl_s[ksw(j4*16 + rw, ks*32 + kq)];
        f32x4 t = mfma16(qcl[ks], bh_, qkacc[j2]);
        t = mfma16(qch[ks], bl_, t);
        qkacc[j2] = mfma16(qch[ks], bh_, t);
      }
      bf16x8 wh_ = *(const bf16x8*)&Wh[(jh*16 + rw)*WSTR + ks*32 + kq];
      bf16x8 wl_ = *(const bf16x8*)&Wl[(jh*16 + rw)*WSTR + ks*32 + kq];
      f32x4 t = mfma16(qcl[ks], wh_, zqacc);
      t = mfma16(qch[ks], wl_, t);
      zqacc = mfma16(qch[ks], wh_, t);
    }
    // ---- prefetch q for chunk n+1 (q dead after zq) ----
    if (n < 63){
      const size_t qg2 = (rowbase + tbase + 64 + tw*16 + rw) * 2048 + (size_t)h*128;
#pragma unroll
      for (int ks = 0; ks < 4; ks++){
        qch[ks] = *(const bf16x8*)(qh + qg2 + ks*32 + kq);
        qcl[ks] = *(const bf16x8*)(ql + qg2 + ks*32 + kq);
      }
    }
    // ---- e finalize: e -= v, pack (h<<16|l), b64 stores to epk/ewpk ----
    {
      const int vv = jh*16 + ccol;
      const int t0 = tw*16 + cquad*4;
      u32 pe[4], pw[4];
#pragma unroll
      for (int r = 0; r < 4; r++){
        int t = t0 + r;
        float e = eacc[r] - v_s[t*36 + vv];
        u16b h1, l1; split2(e, h1, l1);
        pe[r] = ((u32)h1 << 16) | l1;
        float ew = e * dec_s[128 + t];
        u16b h2, l2; split2(ew, h2, l2);
        pw[r] = ((u32)h2 << 16) | l2;
      }
      const int tS = t0 ^ ((vv & 7) << 3);
      uint2 w0; w0.x = pe[0]; w0.y = pe[1];
      uint2 w1; w1.x = pe[2]; w1.y = pe[3];
      *(uint2*)&epk[vv*68 + tS]     = w0;
      *(uint2*)&epk[vv*68 + tS + 2] = w1;
      uint2 w2; w2.x = pw[0]; w2.y = pw[1];
      uint2 w3; w3.x = pw[2]; w3.y = pw[3];
      *(uint2*)&ewpk[vv*68 + tS]     = w2;
      *(uint2*)&ewpk[vv*68 + tS + 2] = w3;
    }
    // ---- S = qk * beta * th[j], tril, swizzled split store ----
#pragma unroll
    for (int j2 = 0; j2 < 2; j2++)
#pragma unroll
      for (int r = 0; r < 4; r++){
        int t  = tw*16 + cquad*4 + r;
        int jj = (jh*2 + j2)*16 + ccol;
        float s = 0.f;
        if (jj <= t)
          s = qkacc[j2][r] * __expf(fminf(dec_s[t] - dec_s[jj], 0.f)) * dec_s[192 + jj];
        u16b h1, l1; split2(s, h1, l1);
        int jjs = jj ^ (((t >> 2) & 7) << 3);
        Sh_s[t*72 + jjs] = h1;  Sl_s[t*72 + jjs] = l1;
      }
    __syncthreads();                    // e/ew/S visible to all waves

    // ---- Se = S @ e (rows tw, cols jh-half) ----
    f32x4 seacc = {};
#pragma unroll
    for (int ks2 = 0; ks2 < 2; ks2++){
      const int srow = tw*16 + rw;
      const int scol2 = (ks2*32 + kq) ^ (((srow >> 2) & 7) << 3);
      bf16x8 ah = *(const bf16x8*)&Sh_s[srow*72 + scol2];
      bf16x8 al = *(const bf16x8*)&Sl_s[srow*72 + scol2];
      const int erow = jh*16 + rw;
      const int ecol = (ks2*32 + kq) ^ ((erow & 7) << 3);
      bf16x8 bh_, bl_;
      unpack8(&epk[erow*68 + ecol], bh_, bl_);
      f32x4 t = mfma16(al, bh_, seacc);
      t = mfma16(ah, bl_, t);
      seacc = mfma16(ah, bh_, t);
    }
    // ---- z -> vo in place (stores are fire-and-forget) ----
#pragma unroll
    for (int r = 0; r < 4; r++){
      int t  = tw*16 + cquad*4 + r;
      int vv = jh*16 + ccol;
      float z = dec_s[64 + t]*zqacc[r] - seacc[r];
      vo[((rowbase + tbase + t)*16 + h)*128 + v0 + vv] = z;
    }
    // ---- dw: A = ew^T rows (mi), B = packed kT rows (kcol) ----
    f32x4 dwacc[2] = {};
    const int kcol = wid*16 + rw;
    const int kx2  = ((kcol >> 3) & 3) << 3;
#pragma unroll
    for (int ks2 = 0; ks2 < 2; ks2++){
      bf16x8 bh_, bl_;
      unpack8(&kTp[kcol*68 + ((ks2*32 + kq) ^ kx2)], bh_, bl_);
#pragma unroll
      for (int mi = 0; mi < 2; mi++){
        const int arow = mi*16 + rw;
        const int acol = (ks2*32 + kq) ^ ((arow & 7) << 3);
        bf16x8 amh, aml;
        unpack8(&ewpk[arow*68 + acol], amh, aml);
        f32x4 t = mfma16(aml, bh_, dwacc[mi]);
        t = mfma16(amh, bl_, t);
        dwacc[mi] = mfma16(amh, bh_, t);
      }
    }
    // ---- W <- W*elt63 - dw (8 disjoint elems/lane) ----
    float dfac = dec_s[64 + 63];
#pragma unroll
    for (int mi = 0; mi < 2; mi++)
#pragma unroll
      for (int r = 0; r < 4; r++){
        int vv = mi*16 + cquad*4 + r;
        int kk = wid*16 + ccol;
        int idx = vv*WSTR + kk;
        float w = bf2f(Wh[idx]) + bf2f(Wl[idx]);
        w = w*dfac - dwacc[mi][r];
        u16b h1, l1; split2(w, h1, l1);
        Wh[idx] = h1; Wl[idx] = l1;
      }
  }
}
#undef WSTR

// ---------------------------------------------------------------------------
// Gated RMSNorm, f32 in -> split bf16 out.
// ---------------------------------------------------------------------------
__global__ __launch_bounds__(256) void norm_kernel(
    const float* __restrict__ outs, const float* __restrict__ g,
    const float* __restrict__ nw, u16b* __restrict__ ogh, u16b* __restrict__ ogl)
{
  const int bt = blockIdx.x;
  const int tid = threadIdx.x;
  size_t base = (size_t)bt*2048 + (size_t)tid*8;
  float4 x0 = *(const float4*)(outs + base);
  float4 x1 = *(const float4*)(outs + base + 4);
  float x[8] = {x0.x,x0.y,x0.z,x0.w,x1.x,x1.y,x1.z,x1.w};
  float ss = 0.f;
#pragma unroll
  for (int i = 0; i < 8; i++) ss += x[i]*x[i];
#pragma unroll
  for (int off = 1; off < 16; off <<= 1) ss += __shfl_xor(ss, off);  // 16-lane head
  float rs = rsqrtf(ss*(1.f/128.f) + 1e-5f);
  float4 g0 = *(const float4*)(g + base);
  float4 g1 = *(const float4*)(g + base + 4);
  float gg[8] = {g0.x,g0.y,g0.z,g0.w,g1.x,g1.y,g1.z,g1.w};
  int nwb = (tid & 15)*8;
  u16b oh[8], ol[8];
#pragma unroll
  for (int i = 0; i < 8; i++){
    float sig = 1.f / (1.f + __expf(-gg[i]));
    float v = x[i]*rs*nw[nwb+i]*gg[i]*sig;
    split2(v, oh[i], ol[i]);
  }
  *(uint4*)(ogh + base) = *(const uint4*)oh;
  *(uint4*)(ogl + base) = *(const uint4*)ol;
}

// ---------------------------------------------------------------------------
extern "C" void kernel_launch(void* const* d_in, const int* in_sizes, int n_in,
                              void* d_out, int out_size, void* d_ws, size_t ws_size,
                              hipStream_t stream)
{
  (void)in_sizes; (void)n_in; (void)out_size; (void)ws_size;
  const float* x    = (const float*)d_in[0];
  const float* Wq   = (const float*)d_in[1];
  const float* Wk   = (const float*)d_in[2];
  const float* Wv   = (const float*)d_in[3];
  const float* Weta = (const float*)d_in[4];
  const float* Wth  = (const float*)d_in[5];
  const float* Wg   = (const float*)d_in[6];
  const float* nw   = (const float*)d_in[7];
  const float* Wo   = (const float*)d_in[8];
  float* out = (float*)d_out;

  const size_t SZ = (size_t)8192*2048;      // activation elems
  const size_t WZ = (size_t)2048*2048;      // weight elems
  const size_t DS = (size_t)2*16*4096;      // decay arrays (B,H,T)
  u16b* ws = (u16b*)d_ws;
  u16b* qhb = ws;            u16b* qlb = qhb + SZ;
  u16b* khb = qlb + SZ;      u16b* klb = khb + SZ;
  float* vob  = (float*)(klb + SZ);         // v, then outs in place
  float* etab = vob + SZ;
  float* thb  = etab + DS;
  float* lecb = thb  + DS;
  float* eltb = lecb + DS;
  float* wtb  = eltb + DS;
  float* gfb  = (float*)khb;                // g f32 after scan (spans kh+kl)
  u16b* ogh = qhb; u16b* ogl = qlb;         // og reuses q slot

  // x split lives in d_out (exactly 2*SZ u16 = out_size); dead before final gemm
  u16b* xh = (u16b*)d_out;   u16b* xl = xh + SZ;
  // weight splits float through dead regions (16.8 MB each, lifetimes checked):
  u16b* wsQh = khb;        u16b* wsQl = khb + WZ;   // dead when gemm k writes kh
  u16b* wsKh = (u16b*)vob; u16b* wsKl = wsKh + WZ;  // dead when gemm v writes vob
  u16b* wsGh = qhb;        u16b* wsGl = qhb + WZ;   // q dead after scan; dead before norm
  u16b* wsOh = khb;        u16b* wsOl = khb + WZ;   // gfb dead after norm

  dim3 gg(1024);
  split_kernel<<<8192, 256, 0, stream>>>(x, xh, xl, (int)(SZ/8));
  etatheta_kernel<<<8192, 256, 0, stream>>>(x, Weta, Wth, etab, thb);
  decay_kernel<<<dim3(32,64), 64, 0, stream>>>(etab, thb, lecb, eltb, wtb);

  split_kernel<<<2048, 256, 0, stream>>>(Wq, wsQh, wsQl, (int)(WZ/8));
  gemm3v<1,0><<<gg, 256, 0, stream>>>(xh, xl, wsQh, wsQl, nullptr,
                                      qhb, qlb, nullptr,
                                      8192, 2048, 2048, 0.08838834764831843f);
  split_kernel<<<2048, 256, 0, stream>>>(Wk, wsKh, wsKl, (int)(WZ/8));
  gemm3v<1,0><<<gg, 256, 0, stream>>>(xh, xl, wsKh, wsKl, nullptr,
                                      khb, klb, nullptr,
                                      8192, 2048, 2048, 1.f);
  gemm3v<0,1><<<gg, 256, 0, stream>>>(xh, xl, nullptr, nullptr, Wv,
                                      nullptr, nullptr, vob,
                                      8192, 2048, 2048, 1.f);
  scan_kernel<<<dim3(32,4), 512, 0, stream>>>(qhb, qlb, khb, klb,
                                              lecb, eltb, wtb, thb, vob);
  split_kernel<<<2048, 256, 0, stream>>>(Wg, wsGh, wsGl, (int)(WZ/8));
  gemm3v<1,1><<<gg, 256, 0, stream>>>(xh, xl, wsGh, wsGl, nullptr,
                                      nullptr, nullptr, gfb,
                                      8192, 2048, 2048, 1.f);
  norm_kernel<<<8192, 256, 0, stream>>>(vob, gfb, nw, ogh, ogl);
  split_kernel<<<2048, 256, 0, stream>>>(Wo, wsOh, wsOl, (int)(WZ/8));
  gemm3v<1,1><<<gg, 256, 0, stream>>>(ogh, ogl, wsOh, wsOl, nullptr,
                                      nullptr, nullptr, out,
                                      8192, 2048, 2048, 1.f);
}